// Round 1
// 914.025 us; speedup vs baseline: 1.0480x; 1.0480x over previous
//
#include <hip/hip_runtime.h>
#include <hip/hip_bf16.h>

// DeepSeek MoE: B=2,T=2048,D=2048,H=1408,E=16,S=2,TOP_K=2
// T_tot = 4096 tokens. Out = [4096*2048 f32] ++ [aux f32]

#define T_TOT   4096
#define DMODEL  2048
#define HDIM    1408
#define NEXP    16
#define MAXSLOT 10240   // 8192 real slots + pad to 128 per expert
#define MAXTILE 80

typedef short     bf16x8_t  __attribute__((ext_vector_type(8)));
typedef float     f32x4_t   __attribute__((ext_vector_type(4)));
typedef ushort    u16x8_t   __attribute__((ext_vector_type(8)));

__device__ __forceinline__ ushort f2bf(float f) {
    unsigned u = __float_as_uint(f);
    u += 0x7fffu + ((u >> 16) & 1u);   // RNE
    return (ushort)(u >> 16);
}
__device__ __forceinline__ float bf2f(ushort b) { return __uint_as_float((unsigned)b << 16); }
__device__ __forceinline__ float silu(float v) { return v / (1.0f + __expf(-v)); }

__device__ __forceinline__ void async16(const ushort* g, ushort* l) {
    __builtin_amdgcn_global_load_lds((const __attribute__((address_space(1))) void*)g,
                                     (__attribute__((address_space(3))) void*)l, 16, 0, 0);
}

// ---------------- small utility kernels ----------------

__global__ void init_kernel(int* cnt, double* ps, double* ls) {
    if (threadIdx.x < NEXP) { cnt[threadIdx.x] = 0; ps[threadIdx.x] = 0.0; ls[threadIdx.x] = 0.0; }
}

__global__ __launch_bounds__(256) void cvt_bf16(const float* __restrict__ src, ushort* __restrict__ dst) {
    size_t i = ((size_t)blockIdx.x * 256 + threadIdx.x) * 4;
    float4 v = *(const float4*)(src + i);
    ushort4 o; o.x = f2bf(v.x); o.y = f2bf(v.y); o.z = f2bf(v.z); o.w = f2bf(v.w);
    *(ushort4*)(dst + i) = o;
}

// src [R,C] f32 (batched) -> dst [C,R] bf16, dst row-stride ldd. 64x64 tiles.
// Read: 16 lanes x float4 = 256B rows. Write: 8 lanes x 16B = 128B rows.
__global__ __launch_bounds__(256) void transpose_cvt(const float* __restrict__ src, ushort* __restrict__ dst,
                                                     int R, int C, long sbatch, long dbatch, int ldd) {
    __shared__ ushort t[64][72];   // +8 ushort pad breaks bank-conflict stride
    const float* s = src + (long)blockIdx.z * sbatch;
    ushort* d = dst + (long)blockIdx.z * dbatch;
    int c0 = blockIdx.x * 64, r0 = blockIdx.y * 64;
    int tx = threadIdx.x & 15, ty = threadIdx.x >> 4;
#pragma unroll
    for (int i = 0; i < 4; i++) {
        int r = ty + i * 16;
        float4 v = *(const float4*)(s + (size_t)(r0 + r) * C + c0 + tx * 4);
        ushort4 o; o.x = f2bf(v.x); o.y = f2bf(v.y); o.z = f2bf(v.z); o.w = f2bf(v.w);
        *(ushort4*)&t[r][tx * 4] = o;
    }
    __syncthreads();
    int cx = threadIdx.x & 7, cy = threadIdx.x >> 3;
#pragma unroll
    for (int i = 0; i < 2; i++) {
        int cc = cy + i * 32;
        u16x8_t o;
#pragma unroll
        for (int j = 0; j < 8; j++) o[j] = t[cx * 8 + j][cc];
        *(u16x8_t*)(d + (size_t)(c0 + cc) * ldd + r0 + cx * 8) = o;
    }
}

// ---------------- router v2 ----------------
// f32 per-lane partial dot products (32 terms/lane -> abs err ~1e-7, far below the
// ~3e-4 minimum top-2/3 logit gap over 4096 tokens, so ranking is identical to the
// fp64 version), fp64 cross-lane combine + softmax + aux. 2 tokens per wave,
// float4 x loads, fully unrolled; lane-parallel softmax/top-2 over 16 lanes.

__global__ __launch_bounds__(256) void router_kernel(const float* __restrict__ x, const float* __restrict__ gw,
                                                     int* __restrict__ topk_idx, float* __restrict__ topk_w,
                                                     double* __restrict__ probs_sum, double* __restrict__ logits_sum,
                                                     int* __restrict__ cnt) {
    const int wv = threadIdx.x >> 6, l = threadIdx.x & 63;
    const int tBase = blockIdx.x * 8 + wv * 2;     // 4 waves x 2 tokens = 8 tokens/block

    float acc0[NEXP], acc1[NEXP];
#pragma unroll
    for (int e = 0; e < NEXP; e++) { acc0[e] = 0.f; acc1[e] = 0.f; }

    const float* x0 = x + (size_t)tBase * DMODEL;
    const float* x1 = x0 + DMODEL;

#pragma unroll
    for (int i = 0; i < 8; i++) {
        const int d0 = i * 256 + l * 4;            // this lane's 4 consecutive dims
        float4 xa = *(const float4*)(x0 + d0);
        float4 xb = *(const float4*)(x1 + d0);
        const float4* g = (const float4*)(gw + (size_t)d0 * NEXP);
        float gf[64];
#pragma unroll
        for (int j = 0; j < 16; j++) {
            float4 t = g[j];
            gf[4 * j] = t.x; gf[4 * j + 1] = t.y; gf[4 * j + 2] = t.z; gf[4 * j + 3] = t.w;
        }
        const float xs0[4] = {xa.x, xa.y, xa.z, xa.w};
        const float xs1[4] = {xb.x, xb.y, xb.z, xb.w};
#pragma unroll
        for (int r = 0; r < 4; r++)
#pragma unroll
            for (int e = 0; e < NEXP; e++) {
                acc0[e] += xs0[r] * gf[r * 16 + e];
                acc1[e] += xs1[r] * gf[r * 16 + e];
            }
    }

    // two f32 butterfly levels: lane l now holds the sum over lanes {l&15, +16, +32, +48}
#pragma unroll
    for (int e = 0; e < NEXP; e++) {
        acc0[e] += __shfl_xor(acc0[e], 32); acc0[e] += __shfl_xor(acc0[e], 16);
        acc1[e] += __shfl_xor(acc1[e], 32); acc1[e] += __shfl_xor(acc1[e], 16);
    }

    __shared__ float  sred[4][2][16][17];          // [wave][tok][srcGroup][expert], +1 pad
    __shared__ double sp[4][2][NEXP], sl[4][2][NEXP];

    if (l < 16) {
#pragma unroll
        for (int e = 0; e < NEXP; e++) { sred[wv][0][l][e] = acc0[e]; sred[wv][1][l][e] = acc1[e]; }
    }
    __syncthreads();

    if (l < 32) {
        const int tok = l >> 4, e = l & 15;        // lane (tok,e) owns expert e of token tok
        double lg = 0.0;
#pragma unroll
        for (int g = 0; g < 16; g++) lg += (double)sred[wv][tok][g][e];   // conflict-free (pad 17)

        // softmax over the 16-lane group (xor masks <16 stay inside the group)
        double m = lg;
#pragma unroll
        for (int off = 8; off; off >>= 1) { double o = __shfl_xor(m, off); m = o > m ? o : m; }
        double pe = exp(lg - m);
        double ss = pe;
#pragma unroll
        for (int off = 8; off; off >>= 1) ss += __shfl_xor(ss, off);
        double p = pe / ss;

        // top-1
        double v = p; int ie = e;
#pragma unroll
        for (int off = 8; off; off >>= 1) {
            double ov = __shfl_xor(v, off); int oi = __shfl_xor(ie, off);
            if (ov > v || (ov == v && oi < ie)) { v = ov; ie = oi; }
        }
        // top-2
        double v2 = (e == ie) ? -1.0 : p; int ie2 = e;
#pragma unroll
        for (int off = 8; off; off >>= 1) {
            double ov = __shfl_xor(v2, off); int oi = __shfl_xor(ie2, off);
            if (ov > v2 || (ov == v2 && oi < ie2)) { v2 = ov; ie2 = oi; }
        }

        sp[wv][tok][e] = p; sl[wv][tok][e] = lg;

        if (e == 0) {
            int t = tBase + tok;
            double s2 = v + v2;
            topk_idx[t * 2] = ie;  topk_idx[t * 2 + 1] = ie2;
            topk_w[t * 2] = (float)(v / s2); topk_w[t * 2 + 1] = (float)(v2 / s2);
            atomicAdd(&cnt[ie], 1); atomicAdd(&cnt[ie2], 1);
        }
    }
    __syncthreads();

    if (threadIdx.x < NEXP) {
        int e = threadIdx.x;
        double ps = 0.0, ls = 0.0;
#pragma unroll
        for (int w = 0; w < 4; w++) { ps += sp[w][0][e] + sp[w][1][e]; ls += sl[w][0][e] + sl[w][1][e]; }
        atomicAdd(&probs_sum[e], ps); atomicAdd(&logits_sum[e], ls);
    }
}

__global__ void setup_kernel(const int* __restrict__ cnt, int* __restrict__ cursor,
                             int* __restrict__ tile_expert, int* __restrict__ tile_row, int* __restrict__ meta,
                             int* __restrict__ slot_token, float* __restrict__ slot_w,
                             const double* __restrict__ probs_sum, const double* __restrict__ logits_sum,
                             float* __restrict__ out_aux) {
    if (threadIdx.x == 0) {
        int off = 0, nt = 0;
        for (int e = 0; e < NEXP; e++) {
            cursor[e] = off;
            int tiles = (cnt[e] + 127) >> 7;
            for (int j = 0; j < tiles; j++) { tile_expert[nt] = e; tile_row[nt] = off + j * 128; nt++; }
            off += tiles * 128;
        }
        meta[0] = nt; meta[1] = off;
        double aux = 0.0;
        for (int e = 0; e < NEXP; e++)
            aux += (probs_sum[e] / (double)T_TOT) * (logits_sum[e] / (double)T_TOT);
        out_aux[0] = (float)(aux * (double)NEXP);
    }
    __syncthreads();
    for (int i = threadIdx.x; i < MAXSLOT; i += 256) { slot_token[i] = 0; slot_w[i] = 0.0f; }
}

__global__ void scatter_kernel(const int* __restrict__ topk_idx, const float* __restrict__ topk_w,
                               int* __restrict__ cursor, int* __restrict__ slot_token, float* __restrict__ slot_w,
                               int* __restrict__ slot_of) {
    int t = blockIdx.x * 256 + threadIdx.x;
#pragma unroll
    for (int k = 0; k < 2; k++) {
        int e = topk_idx[t * 2 + k];
        int pos = atomicAdd(&cursor[e], 1);
        slot_token[pos] = t;
        slot_w[pos] = topk_w[t * 2 + k];
        slot_of[t * 2 + k] = pos;
    }
}

// ---------------- GEMM core: 128x128 tile, BK=32, 4 waves, mfma 16x16x32 bf16 ----------------
// Double-buffered LDS (2 x 16KB halves), ONE barrier per K-iter: prefetch tile k+1
// into the other half before computing tile k, so the barrier's vmcnt(0) drain
// lands after a full compute phase of overlap.

template<bool INDIRECT_A>
__device__ __forceinline__ void gemm_tile_core(const ushort* __restrict__ A, const ushort* __restrict__ B,
                                               int lda, int ldb, int K, int m0, int n0,
                                               const int* __restrict__ rowmap,
                                               f32x4_t acc[4][4], ushort* lds) {
    const int tid = threadIdx.x;
    const int w = tid >> 6, l = tid & 63;
    const int c0 = w * 2, c1 = c0 + 1;       // each wave stages 2 of 8 1KB chunks of A and of B
    const int subrow = l >> 2;
    const int kc = (l & 3) * 8;
    int ar0 = c0 * 16 + subrow, ar1 = c1 * 16 + subrow;
    long ga0, ga1;
    if (INDIRECT_A) { ga0 = (long)rowmap[m0 + ar0]; ga1 = (long)rowmap[m0 + ar1]; }
    else            { ga0 = (long)(m0 + ar0);       ga1 = (long)(m0 + ar1); }
    const ushort* pa0 = A + ga0 * lda + kc;
    const ushort* pa1 = A + ga1 * lda + kc;
    const ushort* pb0 = B + (long)(n0 + ar0) * ldb + kc;
    const ushort* pb1 = B + (long)(n0 + ar1) * ldb + kc;
    const int wm = w & 1, wn = w >> 1;
    const int lrow = l & 15, quad = l >> 4;

    // prologue: stage k=0 into half 0
    {
        ushort* d0 = lds + c0 * 512;
        ushort* d1 = lds + c1 * 512;
        async16(pa0, d0); async16(pa1, d1);
        async16(pb0, d0 + 4096); async16(pb1, d1 + 4096);
    }
    int cur = 0;
    for (int kt = 0; kt < K; kt += 32) {
        __syncthreads();                     // half `cur` staged (vmcnt drained here)
        if (kt + 32 < K) {                   // prefetch next tile into other half
            pa0 += 32; pa1 += 32; pb0 += 32; pb1 += 32;
            ushort* e0 = lds + (cur ^ 1) * 8192 + c0 * 512;
            ushort* e1 = lds + (cur ^ 1) * 8192 + c1 * 512;
            async16(pa0, e0); async16(pa1, e1);
            async16(pb0, e0 + 4096); async16(pb1, e1 + 4096);
        }
        const ushort* As = lds + cur * 8192;
        const ushort* Bs = As + 4096;
        bf16x8_t a[4], b[4];
#pragma unroll
        for (int mi = 0; mi < 4; mi++)
            a[mi] = *(const bf16x8_t*)(As + (wm * 64 + mi * 16 + lrow) * 32 + quad * 8);
#pragma unroll
        for (int ni = 0; ni < 4; ni++)
            b[ni] = *(const bf16x8_t*)(Bs + (wn * 64 + ni * 16 + lrow) * 32 + quad * 8);
#pragma unroll
        for (int mi = 0; mi < 4; mi++)
#pragma unroll
            for (int ni = 0; ni < 4; ni++)
                acc[mi][ni] = __builtin_amdgcn_mfma_f32_16x16x32_bf16(a[mi], b[ni], acc[mi][ni], 0, 0, 0);
        cur ^= 1;
    }
}

// MODE 0: silu -> bf16 store (shared GEMM1, z over S). MODE 2: f32 store (shared GEMM2).
template<int MODE>
__global__ __launch_bounds__(256, 3) void gemm_dense(const ushort* __restrict__ A, const ushort* __restrict__ B,
                                                     void* __restrict__ C, int lda, int ldb, int ldc, int K,
                                                     long bStride, int cZOff) {
    __shared__ ushort lds[16384];
    int m0 = blockIdx.x * 128, n0 = blockIdx.y * 128;
    const ushort* Bz = B + (long)blockIdx.z * bStride;
    f32x4_t acc[4][4];
#pragma unroll
    for (int mi = 0; mi < 4; mi++)
#pragma unroll
        for (int ni = 0; ni < 4; ni++) acc[mi][ni] = (f32x4_t){0.f, 0.f, 0.f, 0.f};
    gemm_tile_core<false>(A, Bz, lda, ldb, K, m0, n0, nullptr, acc, lds);

    const int w = threadIdx.x >> 6, l = threadIdx.x & 63;
    const int wm = w & 1, wn = w >> 1, quad = l >> 4, lcol = l & 15;
    int colBase = (int)blockIdx.z * cZOff + n0 + wn * 64;
#pragma unroll
    for (int mi = 0; mi < 4; mi++) {
        int rowb = m0 + wm * 64 + mi * 16 + quad * 4;
#pragma unroll
        for (int ni = 0; ni < 4; ni++) {
            int col = colBase + ni * 16 + lcol;
#pragma unroll
            for (int r = 0; r < 4; r++) {
                float v = acc[mi][ni][r];
                if (MODE == 0) ((ushort*)C)[(long)(rowb + r) * ldc + col] = f2bf(silu(v));
                else           ((float*)C)[(long)(rowb + r) * ldc + col] = v;
            }
        }
    }
}

// MODE 1: routed GEMM1 — A rows gathered via slot_token, silu -> bf16 to hg (slot-major).
// MODE 3: routed GEMM2 — A = hg direct; epilogue stores w_slot * acc as bf16 into ro[slot]
//         (plain stores; combine_kernel gathers per token afterwards — NO atomics).
template<int MODE>
__global__ __launch_bounds__(256, 3) void gemm_grouped(const ushort* __restrict__ A, const ushort* __restrict__ B,
                                                       void* __restrict__ C, int lda, int ldb, int ldc, int K,
                                                       long bExpertStride,
                                                       const int* __restrict__ tile_expert,
                                                       const int* __restrict__ tile_row,
                                                       const int* __restrict__ meta,
                                                       const int* __restrict__ slot_token,
                                                       const float* __restrict__ slot_w) {
    if ((int)blockIdx.x >= meta[0]) return;
    __shared__ ushort lds[16384];
    int e = tile_expert[blockIdx.x];
    int m0 = tile_row[blockIdx.x];
    int n0 = blockIdx.y * 128;
    const ushort* Be = B + (long)e * bExpertStride;
    f32x4_t acc[4][4];
#pragma unroll
    for (int mi = 0; mi < 4; mi++)
#pragma unroll
        for (int ni = 0; ni < 4; ni++) acc[mi][ni] = (f32x4_t){0.f, 0.f, 0.f, 0.f};
    gemm_tile_core<MODE == 1>(A, Be, lda, ldb, K, m0, n0, slot_token, acc, lds);

    const int w = threadIdx.x >> 6, l = threadIdx.x & 63;
    const int wm = w & 1, wn = w >> 1, quad = l >> 4, lcol = l & 15;
#pragma unroll
    for (int mi = 0; mi < 4; mi++) {
        int rowb = m0 + wm * 64 + mi * 16 + quad * 4;
#pragma unroll
        for (int ni = 0; ni < 4; ni++) {
            int col = n0 + wn * 64 + ni * 16 + lcol;
#pragma unroll
            for (int r = 0; r < 4; r++) {
                float v = acc[mi][ni][r];
                int row = rowb + r;
                if (MODE == 1) {
                    ((ushort*)C)[(long)row * ldc + col] = f2bf(silu(v));
                } else {
                    float wt = slot_w[row];            // 0 for pad slots
                    ((ushort*)C)[(long)row * ldc + col] = f2bf(v * wt);
                }
            }
        }
    }
}

// out[t,:] += ro[slot1(t),:] + ro[slot2(t),:]   (weights already folded into ro)
__global__ __launch_bounds__(256) void combine_kernel(float* __restrict__ out, const ushort* __restrict__ ro,
                                                      const int* __restrict__ slot_of) {
    int t = blockIdx.x;
    int s1 = slot_of[t * 2], s2 = slot_of[t * 2 + 1];
    const u16x8_t* r1 = (const u16x8_t*)(ro + (size_t)s1 * DMODEL);
    const u16x8_t* r2 = (const u16x8_t*)(ro + (size_t)s2 * DMODEL);
    int i = threadIdx.x;                      // DMODEL/8 = 256 exactly
    u16x8_t a = r1[i], b = r2[i];
    float4* o = (float4*)(out + (size_t)t * DMODEL) + i * 2;
    float4 o0 = o[0], o1 = o[1];
    o0.x += bf2f(a[0]) + bf2f(b[0]); o0.y += bf2f(a[1]) + bf2f(b[1]);
    o0.z += bf2f(a[2]) + bf2f(b[2]); o0.w += bf2f(a[3]) + bf2f(b[3]);
    o1.x += bf2f(a[4]) + bf2f(b[4]); o1.y += bf2f(a[5]) + bf2f(b[5]);
    o1.z += bf2f(a[6]) + bf2f(b[6]); o1.w += bf2f(a[7]) + bf2f(b[7]);
    o[0] = o0; o[1] = o1;
}

// ---------------- launch ----------------

extern "C" void kernel_launch(void* const* d_in, const int* in_sizes, int n_in,
                              void* d_out, int out_size, void* d_ws, size_t ws_size,
                              hipStream_t stream) {
    const float* x   = (const float*)d_in[0];
    const float* gw  = (const float*)d_in[1];
    const float* sw1 = (const float*)d_in[2];
    const float* sw2 = (const float*)d_in[3];
    const float* ew1 = (const float*)d_in[4];
    const float* ew2 = (const float*)d_in[5];
    float* out = (float*)d_out;

    char* p = (char*)d_ws;
    auto alloc = [&](size_t bytes) { char* r = p; p += (bytes + 511) & ~(size_t)511; return r; };
    ushort* xb    = (ushort*)alloc((size_t)T_TOT * DMODEL * 2);
    ushort* w1t   = (ushort*)alloc((size_t)2 * HDIM * DMODEL * 2);
    ushort* w2t   = (ushort*)alloc((size_t)DMODEL * 2 * HDIM * 2);
    ushort* ew1t  = (ushort*)alloc((size_t)NEXP * HDIM * DMODEL * 2);
    ushort* ew2t  = (ushort*)alloc((size_t)NEXP * DMODEL * HDIM * 2);
    ushort* h     = (ushort*)alloc((size_t)T_TOT * 2 * HDIM * 2);
    ushort* hg    = (ushort*)alloc((size_t)MAXSLOT * HDIM * 2);
    ushort* ro    = (ushort*)alloc((size_t)MAXSLOT * DMODEL * 2);   // routed weighted rows, bf16
    int*    slot_token = (int*)alloc(MAXSLOT * 4);
    float*  slot_w     = (float*)alloc(MAXSLOT * 4);
    int*    slot_of    = (int*)alloc(T_TOT * 2 * 4);
    int*    topk_idx   = (int*)alloc(T_TOT * 2 * 4);
    float*  topk_w     = (float*)alloc(T_TOT * 2 * 4);
    int*    cnt        = (int*)alloc(64);
    int*    cursor     = (int*)alloc(64);
    int*    tile_expert= (int*)alloc(512);
    int*    tile_row   = (int*)alloc(512);
    int*    meta       = (int*)alloc(64);
    double* probs_sum  = (double*)alloc(128);
    double* logits_sum = (double*)alloc(128);

    init_kernel<<<1, 64, 0, stream>>>(cnt, probs_sum, logits_sum);
    cvt_bf16<<<(T_TOT * DMODEL) / 1024, 256, 0, stream>>>(x, xb);
    // shared_w1 [2,2048,1408] -> w1t [2,1408,2048]
    transpose_cvt<<<dim3(HDIM / 64, DMODEL / 64, 2), 256, 0, stream>>>(
        sw1, w1t, DMODEL, HDIM, (long)DMODEL * HDIM, (long)HDIM * DMODEL, DMODEL);
    // shared_w2 [2,1408,2048] -> w2t [2048, 2*1408]
    transpose_cvt<<<dim3(DMODEL / 64, HDIM / 64, 2), 256, 0, stream>>>(
        sw2, w2t, HDIM, DMODEL, (long)HDIM * DMODEL, (long)HDIM, 2 * HDIM);
    // expert_w1 [16,2048,1408] -> ew1t [16,1408,2048]
    transpose_cvt<<<dim3(HDIM / 64, DMODEL / 64, NEXP), 256, 0, stream>>>(
        ew1, ew1t, DMODEL, HDIM, (long)DMODEL * HDIM, (long)HDIM * DMODEL, DMODEL);
    // expert_w2 [16,1408,2048] -> ew2t [16,2048,1408]
    transpose_cvt<<<dim3(DMODEL / 64, HDIM / 64, NEXP), 256, 0, stream>>>(
        ew2, ew2t, HDIM, DMODEL, (long)HDIM * DMODEL, (long)DMODEL * HDIM, HDIM);

    router_kernel<<<T_TOT / 8, 256, 0, stream>>>(x, gw, topk_idx, topk_w, probs_sum, logits_sum, cnt);
    setup_kernel<<<1, 256, 0, stream>>>(cnt, cursor, tile_expert, tile_row, meta,
                                        slot_token, slot_w, probs_sum, logits_sum, out + (size_t)T_TOT * DMODEL);
    scatter_kernel<<<T_TOT / 256, 256, 0, stream>>>(topk_idx, topk_w, cursor, slot_token, slot_w, slot_of);

    // shared GEMM1: h[t, s*1408+j] = silu(xb @ w1t[s]^T)
    gemm_dense<0><<<dim3(T_TOT / 128, HDIM / 128, 2), 256, 0, stream>>>(
        xb, w1t, h, DMODEL, DMODEL, 2 * HDIM, DMODEL, (long)HDIM * DMODEL, HDIM);
    // routed GEMM1: hg[slot, j] = silu(x[slot_token] @ ew1t[e]^T)
    gemm_grouped<1><<<dim3(MAXTILE, HDIM / 128), 256, 0, stream>>>(
        xb, ew1t, hg, DMODEL, DMODEL, HDIM, DMODEL, (long)HDIM * DMODEL,
        tile_expert, tile_row, meta, slot_token, slot_w);
    // shared GEMM2: out[t,d] = h @ w2t^T  (K = 2816 spans both shared experts)
    gemm_dense<2><<<dim3(T_TOT / 128, DMODEL / 128, 1), 256, 0, stream>>>(
        h, w2t, out, 2 * HDIM, 2 * HDIM, DMODEL, 2 * HDIM, 0L, 0);
    // routed GEMM2: ro[slot,d] = w_slot * (hg @ ew2t[e]^T)   — plain bf16 stores
    gemm_grouped<3><<<dim3(MAXTILE, DMODEL / 128), 256, 0, stream>>>(
        hg, ew2t, ro, HDIM, HDIM, DMODEL, HDIM, (long)DMODEL * HDIM,
        tile_expert, tile_row, meta, slot_token, slot_w);
    // combine: out[t] += ro[slot1(t)] + ro[slot2(t)]
    combine_kernel<<<T_TOT, 256, 0, stream>>>(out, ro, slot_of);
}

// Round 2
// 810.951 us; speedup vs baseline: 1.1812x; 1.1271x over previous
//
#include <hip/hip_runtime.h>
#include <hip/hip_bf16.h>

// DeepSeek MoE: B=2,T=2048,D=2048,H=1408,E=16,S=2,TOP_K=2
// T_tot = 4096 tokens. Out = [4096*2048 f32] ++ [aux f32]
// 5 launches: prep(transposes+router+xb) -> plan -> gemm_p1 -> gemm_p2 -> combine

#define T_TOT   4096
#define DMODEL  2048
#define HDIM    1408
#define NEXP    16
#define MAXSLOT 10240   // 8192 real slots + pad to 128 per expert
#define MAXTILE 80
#define RBLK    512     // router blocks (8 tokens each)

typedef short     bf16x8_t  __attribute__((ext_vector_type(8)));
typedef float     f32x4_t   __attribute__((ext_vector_type(4)));
typedef ushort    u16x8_t   __attribute__((ext_vector_type(8)));

__device__ __forceinline__ ushort f2bf(float f) {
    unsigned u = __float_as_uint(f);
    u += 0x7fffu + ((u >> 16) & 1u);   // RNE
    return (ushort)(u >> 16);
}
__device__ __forceinline__ float bf2f(ushort b) { return __uint_as_float((unsigned)b << 16); }
__device__ __forceinline__ float silu(float v) { return v / (1.0f + __expf(-v)); }

__device__ __forceinline__ void async16(const ushort* g, ushort* l) {
    __builtin_amdgcn_global_load_lds((const __attribute__((address_space(1))) void*)g,
                                     (__attribute__((address_space(3))) void*)l, 16, 0, 0);
}

// ---------------- prep mega-kernel: router + 4 weight transposes ----------------

union SMem {
    struct {
        float  sred[4][2][16][17];   // [wave][tok][srcGroup][expert], +1 pad
        double sp[4][2][NEXP];
        double sl[4][2][NEXP];
    } r;
    ushort t[64][72];                // transpose tile, +8 pad
};

// src [z][R][C] f32 -> dst [z-mapped][C][R] bf16 (row stride ldd). 64x64 tiles.
__device__ __forceinline__ void transpose_tile(SMem& sm, int id,
        const float* __restrict__ src, ushort* __restrict__ dst,
        int C, long sbatch, long dbatch, int ldd, int TX, int TY) {
    int z = id / (TX * TY); int rem = id - z * TX * TY;
    int bx = rem % TX, by = rem / TX;
    const float* s = src + (long)z * sbatch;
    ushort* d = dst + (long)z * dbatch;
    int c0 = bx * 64, r0 = by * 64;
    int tx = threadIdx.x & 15, ty = threadIdx.x >> 4;
#pragma unroll
    for (int i = 0; i < 4; i++) {
        int r = ty + i * 16;
        float4 v = *(const float4*)(s + (size_t)(r0 + r) * C + c0 + tx * 4);
        ushort4 o; o.x = f2bf(v.x); o.y = f2bf(v.y); o.z = f2bf(v.z); o.w = f2bf(v.w);
        *(ushort4*)&sm.t[r][tx * 4] = o;
    }
    __syncthreads();
    int cx = threadIdx.x & 7, cy = threadIdx.x >> 3;
#pragma unroll
    for (int i = 0; i < 2; i++) {
        int cc = cy + i * 32;
        u16x8_t o;
#pragma unroll
        for (int j = 0; j < 8; j++) o[j] = sm.t[cx * 8 + j][cc];
        *(u16x8_t*)(d + (size_t)(c0 + cc) * ldd + r0 + cx * 8) = o;
    }
}

// Router: f32 per-lane partials (32 terms/lane, abs err ~1e-7 << min top-2/3 logit gap
// ~3e-4 -> ranking identical to fp64), fp64 cross-lane combine/softmax/top-2.
// Also emits xb (bf16 of x) and per-block prob/logit partial sums (plain stores).
__device__ __forceinline__ void router_block(SMem& sm, int bid,
        const float* __restrict__ x, const float* __restrict__ gw, ushort* __restrict__ xbuf,
        int* __restrict__ topk_idx, float* __restrict__ topk_w,
        double* __restrict__ pparts, double* __restrict__ lparts) {
    const int wv = threadIdx.x >> 6, l = threadIdx.x & 63;
    const int tBase = bid * 8 + wv * 2;            // 4 waves x 2 tokens

    float acc0[NEXP], acc1[NEXP];
#pragma unroll
    for (int e = 0; e < NEXP; e++) { acc0[e] = 0.f; acc1[e] = 0.f; }

    const float* x0 = x + (size_t)tBase * DMODEL;
    const float* x1 = x0 + DMODEL;
    ushort* xo0 = xbuf + (size_t)tBase * DMODEL;
    ushort* xo1 = xo0 + DMODEL;

#pragma unroll
    for (int i = 0; i < 8; i++) {
        const int d0 = i * 256 + l * 4;
        float4 xa = *(const float4*)(x0 + d0);
        float4 xb4 = *(const float4*)(x1 + d0);
        ushort4 oa; oa.x = f2bf(xa.x); oa.y = f2bf(xa.y); oa.z = f2bf(xa.z); oa.w = f2bf(xa.w);
        ushort4 ob; ob.x = f2bf(xb4.x); ob.y = f2bf(xb4.y); ob.z = f2bf(xb4.z); ob.w = f2bf(xb4.w);
        *(ushort4*)(xo0 + d0) = oa;
        *(ushort4*)(xo1 + d0) = ob;
        const float xs0[4] = {xa.x, xa.y, xa.z, xa.w};
        const float xs1[4] = {xb4.x, xb4.y, xb4.z, xb4.w};
#pragma unroll
        for (int r = 0; r < 4; r++) {
            const float4* g = (const float4*)(gw + (size_t)(d0 + r) * NEXP);
            float4 q0 = g[0], q1 = g[1], q2 = g[2], q3 = g[3];
            const float gf[16] = {q0.x, q0.y, q0.z, q0.w, q1.x, q1.y, q1.z, q1.w,
                                  q2.x, q2.y, q2.z, q2.w, q3.x, q3.y, q3.z, q3.w};
#pragma unroll
            for (int e = 0; e < NEXP; e++) {
                acc0[e] += xs0[r] * gf[e];
                acc1[e] += xs1[r] * gf[e];
            }
        }
    }

#pragma unroll
    for (int e = 0; e < NEXP; e++) {
        acc0[e] += __shfl_xor(acc0[e], 32); acc0[e] += __shfl_xor(acc0[e], 16);
        acc1[e] += __shfl_xor(acc1[e], 32); acc1[e] += __shfl_xor(acc1[e], 16);
    }

    if (l < 16) {
#pragma unroll
        for (int e = 0; e < NEXP; e++) { sm.r.sred[wv][0][l][e] = acc0[e]; sm.r.sred[wv][1][l][e] = acc1[e]; }
    }
    __syncthreads();

    if (l < 32) {
        const int tok = l >> 4, e = l & 15;
        double lg = 0.0;
#pragma unroll
        for (int g = 0; g < 16; g++) lg += (double)sm.r.sred[wv][tok][g][e];

        double m = lg;
#pragma unroll
        for (int off = 8; off; off >>= 1) { double o = __shfl_xor(m, off); m = o > m ? o : m; }
        double pe = exp(lg - m);
        double ss = pe;
#pragma unroll
        for (int off = 8; off; off >>= 1) ss += __shfl_xor(ss, off);
        double p = pe / ss;

        double v = p; int ie = e;
#pragma unroll
        for (int off = 8; off; off >>= 1) {
            double ov = __shfl_xor(v, off); int oi = __shfl_xor(ie, off);
            if (ov > v || (ov == v && oi < ie)) { v = ov; ie = oi; }
        }
        double v2 = (e == ie) ? -1.0 : p; int ie2 = e;
#pragma unroll
        for (int off = 8; off; off >>= 1) {
            double ov = __shfl_xor(v2, off); int oi = __shfl_xor(ie2, off);
            if (ov > v2 || (ov == v2 && oi < ie2)) { v2 = ov; ie2 = oi; }
        }

        sm.r.sp[wv][tok][e] = p; sm.r.sl[wv][tok][e] = lg;

        if (e == 0) {
            int t = tBase + tok;
            double s2 = v + v2;
            topk_idx[t * 2] = ie;  topk_idx[t * 2 + 1] = ie2;
            topk_w[t * 2] = (float)(v / s2); topk_w[t * 2 + 1] = (float)(v2 / s2);
        }
    }
    __syncthreads();

    if (threadIdx.x < NEXP) {
        int e = threadIdx.x;
        double ps = 0.0, ls = 0.0;
#pragma unroll
        for (int w = 0; w < 4; w++) { ps += sm.r.sp[w][0][e] + sm.r.sp[w][1][e]; ls += sm.r.sl[w][0][e] + sm.r.sl[w][1][e]; }
        pparts[bid * NEXP + e] = ps;
        lparts[bid * NEXP + e] = ls;
    }
}

// segment boundaries
#define PB0 RBLK                 // 512   router
#define PB1 (PB0 + 1408)         // sw1: 22x32x2
#define PB2 (PB1 + 1408)         // sw2: 32x22x2
#define PB3 (PB2 + 11264)        // ew1: 22x32x16
#define PB4 (PB3 + 11264)        // ew2: 32x22x16  -> grid = 25856

__global__ __launch_bounds__(256) void prep_kernel(
        const float* __restrict__ x, const float* __restrict__ gw,
        const float* __restrict__ sw1, const float* __restrict__ sw2,
        const float* __restrict__ ew1, const float* __restrict__ ew2,
        ushort* __restrict__ xb, ushort* __restrict__ w1t, ushort* __restrict__ w2t,
        ushort* __restrict__ ew1t, ushort* __restrict__ ew2t,
        int* __restrict__ topk_idx, float* __restrict__ topk_w,
        double* __restrict__ pparts, double* __restrict__ lparts) {
    __shared__ SMem sm;
    int bid = blockIdx.x;
    if (bid < PB0) {
        router_block(sm, bid, x, gw, xb, topk_idx, topk_w, pparts, lparts);
    } else if (bid < PB1) {
        transpose_tile(sm, bid - PB0, sw1, w1t, HDIM, (long)DMODEL * HDIM, (long)HDIM * DMODEL,
                       DMODEL, HDIM / 64, DMODEL / 64);
    } else if (bid < PB2) {
        transpose_tile(sm, bid - PB1, sw2, w2t, DMODEL, (long)HDIM * DMODEL, (long)HDIM,
                       2 * HDIM, DMODEL / 64, HDIM / 64);
    } else if (bid < PB3) {
        transpose_tile(sm, bid - PB2, ew1, ew1t, HDIM, (long)DMODEL * HDIM, (long)HDIM * DMODEL,
                       DMODEL, HDIM / 64, DMODEL / 64);
    } else {
        transpose_tile(sm, bid - PB3, ew2, ew2t, DMODEL, (long)HDIM * DMODEL, (long)DMODEL * HDIM,
                       HDIM, DMODEL / 64, HDIM / 64);
    }
}

// ---------------- plan: histogram + tiles + aux + scatter (1 block) ----------------

__global__ __launch_bounds__(1024) void plan_kernel(
        const int* __restrict__ topk_idx, const float* __restrict__ topk_w,
        const double* __restrict__ pparts, const double* __restrict__ lparts,
        int* __restrict__ tile_expert, int* __restrict__ tile_row, int* __restrict__ meta,
        int* __restrict__ slot_token, float* __restrict__ slot_w, int* __restrict__ slot_of,
        float* __restrict__ out_aux) {
    __shared__ int hist[NEXP];
    __shared__ int curs[NEXP];
    __shared__ double pred[32][NEXP], lred[32][NEXP];
    __shared__ double paux[NEXP], laux[NEXP];
    const int tid = threadIdx.x;
    if (tid < NEXP) hist[tid] = 0;
    __syncthreads();
    for (int i = tid; i < T_TOT * 2; i += 1024) atomicAdd(&hist[topk_idx[i]], 1);
    for (int i = tid; i < MAXSLOT; i += 1024) { slot_token[i] = 0; slot_w[i] = 0.0f; }
    if (tid < 512) {
        int e = tid & 15, c = tid >> 4;     // 32 chunks of 16 blocks
        double ps = 0.0, ls = 0.0;
        for (int b = c * 16; b < c * 16 + 16; b++) { ps += pparts[b * NEXP + e]; ls += lparts[b * NEXP + e]; }
        pred[c][e] = ps; lred[c][e] = ls;
    }
    __syncthreads();
    if (tid < NEXP) {
        double ps = 0.0, ls = 0.0;
        for (int c = 0; c < 32; c++) { ps += pred[c][tid]; ls += lred[c][tid]; }
        paux[tid] = ps; laux[tid] = ls;
    }
    __syncthreads();
    if (tid == 0) {
        int off = 0, nt = 0;
        for (int e = 0; e < NEXP; e++) {
            curs[e] = off;
            int tiles = (hist[e] + 127) >> 7;
            for (int j = 0; j < tiles; j++) { tile_expert[nt] = e; tile_row[nt] = off + j * 128; nt++; }
            off += tiles * 128;
        }
        meta[0] = nt; meta[1] = off;
        double aux = 0.0;
        for (int e = 0; e < NEXP; e++)
            aux += (paux[e] / (double)T_TOT) * (laux[e] / (double)T_TOT);
        out_aux[0] = (float)(aux * (double)NEXP);
    }
    __syncthreads();
    for (int i = tid; i < T_TOT * 2; i += 1024) {
        int e = topk_idx[i];
        int pos = atomicAdd(&curs[e], 1);
        slot_token[pos] = i >> 1;
        slot_w[pos] = topk_w[i];
        slot_of[i] = pos;
    }
}

// ---------------- GEMM core: 128x128 tile, BK=32, 4 waves, mfma 16x16x32 bf16 ----------------
// Double-buffered LDS (2 x 16KB halves), ONE barrier per K-iter.

template<bool INDIRECT_A>
__device__ __forceinline__ void gemm_tile_core(const ushort* __restrict__ A, const ushort* __restrict__ B,
                                               int lda, int ldb, int K, int m0, int n0,
                                               const int* __restrict__ rowmap,
                                               f32x4_t acc[4][4], ushort* lds) {
    const int tid = threadIdx.x;
    const int w = tid >> 6, l = tid & 63;
    const int c0 = w * 2, c1 = c0 + 1;       // each wave stages 2 of 8 1KB chunks of A and of B
    const int subrow = l >> 2;
    const int kc = (l & 3) * 8;
    int ar0 = c0 * 16 + subrow, ar1 = c1 * 16 + subrow;
    long ga0, ga1;
    if (INDIRECT_A) { ga0 = (long)rowmap[m0 + ar0]; ga1 = (long)rowmap[m0 + ar1]; }
    else            { ga0 = (long)(m0 + ar0);       ga1 = (long)(m0 + ar1); }
    const ushort* pa0 = A + ga0 * lda + kc;
    const ushort* pa1 = A + ga1 * lda + kc;
    const ushort* pb0 = B + (long)(n0 + ar0) * ldb + kc;
    const ushort* pb1 = B + (long)(n0 + ar1) * ldb + kc;
    const int wm = w & 1, wn = w >> 1;
    const int lrow = l & 15, quad = l >> 4;

    {   // prologue: stage k=0 into half 0
        ushort* d0 = lds + c0 * 512;
        ushort* d1 = lds + c1 * 512;
        async16(pa0, d0); async16(pa1, d1);
        async16(pb0, d0 + 4096); async16(pb1, d1 + 4096);
    }
    int cur = 0;
    for (int kt = 0; kt < K; kt += 32) {
        __syncthreads();                     // half `cur` staged (vmcnt drained here)
        if (kt + 32 < K) {                   // prefetch next tile into other half
            pa0 += 32; pa1 += 32; pb0 += 32; pb1 += 32;
            ushort* e0 = lds + (cur ^ 1) * 8192 + c0 * 512;
            ushort* e1 = lds + (cur ^ 1) * 8192 + c1 * 512;
            async16(pa0, e0); async16(pa1, e1);
            async16(pb0, e0 + 4096); async16(pb1, e1 + 4096);
        }
        const ushort* As = lds + cur * 8192;
        const ushort* Bs = As + 4096;
        bf16x8_t a[4], b[4];
#pragma unroll
        for (int mi = 0; mi < 4; mi++)
            a[mi] = *(const bf16x8_t*)(As + (wm * 64 + mi * 16 + lrow) * 32 + quad * 8);
#pragma unroll
        for (int ni = 0; ni < 4; ni++)
            b[ni] = *(const bf16x8_t*)(Bs + (wn * 64 + ni * 16 + lrow) * 32 + quad * 8);
#pragma unroll
        for (int mi = 0; mi < 4; mi++)
#pragma unroll
            for (int ni = 0; ni < 4; ni++)
                acc[mi][ni] = __builtin_amdgcn_mfma_f32_16x16x32_bf16(a[mi], b[ni], acc[mi][ni], 0, 0, 0);
        cur ^= 1;
    }
}

// P1: [0,704) shared GEMM1 (z over 2 experts) ++ [704, 704+880) routed GEMM1.
__global__ __launch_bounds__(256, 3) void gemm_p1(const ushort* __restrict__ xb,
        const ushort* __restrict__ w1t, const ushort* __restrict__ ew1t,
        ushort* __restrict__ h, ushort* __restrict__ hg,
        const int* __restrict__ tile_expert, const int* __restrict__ tile_row,
        const int* __restrict__ meta, const int* __restrict__ slot_token) {
    __shared__ ushort lds[16384];
    f32x4_t acc[4][4];
#pragma unroll
    for (int mi = 0; mi < 4; mi++)
#pragma unroll
        for (int ni = 0; ni < 4; ni++) acc[mi][ni] = (f32x4_t){0.f, 0.f, 0.f, 0.f};

    const int bid = blockIdx.x;
    ushort* C; int ldc, m0, n0, colBase;
    if (bid < 704) {
        int z = bid / 352, rem = bid % 352;
        m0 = (rem % 32) * 128; n0 = (rem / 32) * 128;
        gemm_tile_core<false>(xb, w1t + (long)z * HDIM * DMODEL, DMODEL, DMODEL, DMODEL,
                              m0, n0, nullptr, acc, lds);
        C = h; ldc = 2 * HDIM; colBase = z * HDIM + n0;
    } else {
        int r = bid - 704;
        int tile = r % MAXTILE; n0 = (r / MAXTILE) * 128;
        if (tile >= meta[0]) return;
        int e = tile_expert[tile]; m0 = tile_row[tile];
        gemm_tile_core<true>(xb, ew1t + (long)e * HDIM * DMODEL, DMODEL, DMODEL, DMODEL,
                             m0, n0, slot_token, acc, lds);
        C = hg; ldc = HDIM; colBase = n0;
    }

    const int w = threadIdx.x >> 6, l = threadIdx.x & 63;
    const int wm = w & 1, wn = w >> 1, quad = l >> 4, lcol = l & 15;
#pragma unroll
    for (int mi = 0; mi < 4; mi++) {
        int rowb = m0 + wm * 64 + mi * 16 + quad * 4;
#pragma unroll
        for (int ni = 0; ni < 4; ni++) {
            int col = colBase + wn * 64 + ni * 16 + lcol;
#pragma unroll
            for (int r = 0; r < 4; r++)
                C[(long)(rowb + r) * ldc + col] = f2bf(silu(acc[mi][ni][r]));
        }
    }
}

// P2: [0,512) shared GEMM2 (f32 -> out) ++ [512, 512+1280) routed GEMM2 (w*acc bf16 -> ro).
__global__ __launch_bounds__(256, 3) void gemm_p2(const ushort* __restrict__ h,
        const ushort* __restrict__ w2t, const ushort* __restrict__ hg, const ushort* __restrict__ ew2t,
        float* __restrict__ out, ushort* __restrict__ ro,
        const int* __restrict__ tile_expert, const int* __restrict__ tile_row,
        const int* __restrict__ meta, const float* __restrict__ slot_w) {
    __shared__ ushort lds[16384];
    f32x4_t acc[4][4];
#pragma unroll
    for (int mi = 0; mi < 4; mi++)
#pragma unroll
        for (int ni = 0; ni < 4; ni++) acc[mi][ni] = (f32x4_t){0.f, 0.f, 0.f, 0.f};

    const int bid = blockIdx.x;
    const int w = threadIdx.x >> 6, l = threadIdx.x & 63;
    const int wm = w & 1, wn = w >> 1, quad = l >> 4, lcol = l & 15;

    if (bid < 512) {
        int m0 = (bid % 32) * 128, n0 = (bid / 32) * 128;
        gemm_tile_core<false>(h, w2t, 2 * HDIM, 2 * HDIM, 2 * HDIM, m0, n0, nullptr, acc, lds);
#pragma unroll
        for (int mi = 0; mi < 4; mi++) {
            int rowb = m0 + wm * 64 + mi * 16 + quad * 4;
#pragma unroll
            for (int ni = 0; ni < 4; ni++) {
                int col = n0 + wn * 64 + ni * 16 + lcol;
#pragma unroll
                for (int r = 0; r < 4; r++)
                    out[(long)(rowb + r) * DMODEL + col] = acc[mi][ni][r];
            }
        }
    } else {
        int r0 = bid - 512;
        int tile = r0 % MAXTILE; int n0 = (r0 / MAXTILE) * 128;
        if (tile >= meta[0]) return;
        int e = tile_expert[tile]; int m0 = tile_row[tile];
        gemm_tile_core<false>(hg, ew2t + (long)e * DMODEL * HDIM, HDIM, HDIM, HDIM,
                              m0, n0, nullptr, acc, lds);
#pragma unroll
        for (int mi = 0; mi < 4; mi++) {
            int rowb = m0 + wm * 64 + mi * 16 + quad * 4;
#pragma unroll
            for (int ni = 0; ni < 4; ni++) {
                int col = n0 + wn * 64 + ni * 16 + lcol;
#pragma unroll
                for (int r = 0; r < 4; r++) {
                    int row = rowb + r;
                    ro[(long)row * DMODEL + col] = f2bf(acc[mi][ni][r] * slot_w[row]);
                }
            }
        }
    }
}

// out[t,:] += ro[slot1(t),:] + ro[slot2(t),:]   (weights already folded into ro)
__global__ __launch_bounds__(256) void combine_kernel(float* __restrict__ out, const ushort* __restrict__ ro,
                                                      const int* __restrict__ slot_of) {
    int t = blockIdx.x;
    int s1 = slot_of[t * 2], s2 = slot_of[t * 2 + 1];
    const u16x8_t* r1 = (const u16x8_t*)(ro + (size_t)s1 * DMODEL);
    const u16x8_t* r2 = (const u16x8_t*)(ro + (size_t)s2 * DMODEL);
    int i = threadIdx.x;                      // DMODEL/8 = 256 exactly
    u16x8_t a = r1[i], b = r2[i];
    float4* o = (float4*)(out + (size_t)t * DMODEL) + i * 2;
    float4 o0 = o[0], o1 = o[1];
    o0.x += bf2f(a[0]) + bf2f(b[0]); o0.y += bf2f(a[1]) + bf2f(b[1]);
    o0.z += bf2f(a[2]) + bf2f(b[2]); o0.w += bf2f(a[3]) + bf2f(b[3]);
    o1.x += bf2f(a[4]) + bf2f(b[4]); o1.y += bf2f(a[5]) + bf2f(b[5]);
    o1.z += bf2f(a[6]) + bf2f(b[6]); o1.w += bf2f(a[7]) + bf2f(b[7]);
    o[0] = o0; o[1] = o1;
}

// ---------------- launch ----------------

extern "C" void kernel_launch(void* const* d_in, const int* in_sizes, int n_in,
                              void* d_out, int out_size, void* d_ws, size_t ws_size,
                              hipStream_t stream) {
    const float* x   = (const float*)d_in[0];
    const float* gw  = (const float*)d_in[1];
    const float* sw1 = (const float*)d_in[2];
    const float* sw2 = (const float*)d_in[3];
    const float* ew1 = (const float*)d_in[4];
    const float* ew2 = (const float*)d_in[5];
    float* out = (float*)d_out;

    char* p = (char*)d_ws;
    auto alloc = [&](size_t bytes) { char* r = p; p += (bytes + 511) & ~(size_t)511; return r; };
    ushort* xb    = (ushort*)alloc((size_t)T_TOT * DMODEL * 2);
    ushort* w1t   = (ushort*)alloc((size_t)2 * HDIM * DMODEL * 2);
    ushort* w2t   = (ushort*)alloc((size_t)DMODEL * 2 * HDIM * 2);
    ushort* ew1t  = (ushort*)alloc((size_t)NEXP * HDIM * DMODEL * 2);
    ushort* ew2t  = (ushort*)alloc((size_t)NEXP * DMODEL * HDIM * 2);
    ushort* h     = (ushort*)alloc((size_t)T_TOT * 2 * HDIM * 2);
    ushort* hg    = (ushort*)alloc((size_t)MAXSLOT * HDIM * 2);
    ushort* ro    = (ushort*)alloc((size_t)MAXSLOT * DMODEL * 2);   // routed weighted rows, bf16
    int*    slot_token = (int*)alloc(MAXSLOT * 4);
    float*  slot_w     = (float*)alloc(MAXSLOT * 4);
    int*    slot_of    = (int*)alloc(T_TOT * 2 * 4);
    int*    topk_idx   = (int*)alloc(T_TOT * 2 * 4);
    float*  topk_w     = (float*)alloc(T_TOT * 2 * 4);
    int*    tile_expert= (int*)alloc(512);
    int*    tile_row   = (int*)alloc(512);
    int*    meta       = (int*)alloc(64);
    double* pparts     = (double*)alloc((size_t)RBLK * NEXP * 8);
    double* lparts     = (double*)alloc((size_t)RBLK * NEXP * 8);

    // 1) transposes + router (+ xb emission, per-block aux partials)
    prep_kernel<<<PB4, 256, 0, stream>>>(x, gw, sw1, sw2, ew1, ew2,
                                         xb, w1t, w2t, ew1t, ew2t,
                                         topk_idx, topk_w, pparts, lparts);
    // 2) histogram + tiles + aux + scatter
    plan_kernel<<<1, 1024, 0, stream>>>(topk_idx, topk_w, pparts, lparts,
                                        tile_expert, tile_row, meta,
                                        slot_token, slot_w, slot_of, out + (size_t)T_TOT * DMODEL);
    // 3) shared GEMM1 + routed GEMM1
    gemm_p1<<<704 + MAXTILE * (HDIM / 128), 256, 0, stream>>>(
        xb, w1t, ew1t, h, hg, tile_expert, tile_row, meta, slot_token);
    // 4) shared GEMM2 + routed GEMM2
    gemm_p2<<<512 + MAXTILE * (DMODEL / 128), 256, 0, stream>>>(
        h, w2t, hg, ew2t, out, ro, tile_expert, tile_row, meta, slot_w);
    // 5) combine: out[t] += ro[slot1(t)] + ro[slot2(t)]
    combine_kernel<<<T_TOT, 256, 0, stream>>>(out, ro, slot_of);
}

// Round 3
// 808.375 us; speedup vs baseline: 1.1850x; 1.0032x over previous
//
#include <hip/hip_runtime.h>
#include <hip/hip_bf16.h>

// DeepSeek MoE: B=2,T=2048,D=2048,H=1408,E=16,S=2,TOP_K=2
// T_tot = 4096 tokens. Out = [4096*2048 f32] ++ [aux f32]
// 5 launches: prep(transposes+router+xb) -> plan -> gemm_p1 -> gemm_p2 -> combine

#define T_TOT   4096
#define DMODEL  2048
#define HDIM    1408
#define NEXP    16
#define MAXSLOT 10240   // 8192 real slots + pad to 128 per expert
#define MAXTILE 80
#define RBLK    512     // router blocks (8 tokens each)

typedef short     bf16x8_t  __attribute__((ext_vector_type(8)));
typedef float     f32x4_t   __attribute__((ext_vector_type(4)));
typedef ushort    u16x8_t   __attribute__((ext_vector_type(8)));

__device__ __forceinline__ ushort f2bf(float f) {
    unsigned u = __float_as_uint(f);
    u += 0x7fffu + ((u >> 16) & 1u);   // RNE
    return (ushort)(u >> 16);
}
__device__ __forceinline__ float bf2f(ushort b) { return __uint_as_float((unsigned)b << 16); }
__device__ __forceinline__ float silu(float v) { return v / (1.0f + __expf(-v)); }

__device__ __forceinline__ void async16(const ushort* g, ushort* l) {
    __builtin_amdgcn_global_load_lds((const __attribute__((address_space(1))) void*)g,
                                     (__attribute__((address_space(3))) void*)l, 16, 0, 0);
}

// ---------------- prep mega-kernel: router + 4 weight transposes ----------------

union SMem {
    struct {
        float  sred[4][2][16][17];   // [wave][tok][srcGroup][expert], +1 pad
        double sp[4][2][NEXP];
        double sl[4][2][NEXP];
    } r;
    ushort t[4096];                  // transpose tile 64x64, XOR-swizzled (no pad)
};

// Swizzled LDS byte offset for logical (row r, col c) of the 64x64 ushort tile.
// byte = r*128 + (c*2 ^ ((r>>3)&7)<<4). Same involution on write and read:
//  - write phase (ushort4 @ c=tx*4): 16 tx-lanes' 8B spans cover all 32 banks, 0 conflict
//  - read phase (scalar @ col cc, rows cx*8+j): bank = bijection over (cy>>1, cx) -> 0 conflict
__device__ __forceinline__ int swz(int r, int c2) {
    return r * 128 + (c2 ^ ((r & 56) << 1));
}

// src [z][R][C] f32 -> dst [z-mapped][C][R] bf16 (row stride ldd). 64x64 tiles.
__device__ __forceinline__ void transpose_tile(ushort* t, int id,
        const float* __restrict__ src, ushort* __restrict__ dst,
        int C, long sbatch, long dbatch, int ldd, int TX, int TY) {
    int z = id / (TX * TY); int rem = id - z * TX * TY;
    int bx = rem % TX, by = rem / TX;
    const float* s = src + (long)z * sbatch;
    ushort* d = dst + (long)z * dbatch;
    int c0 = bx * 64, r0 = by * 64;
    int tx = threadIdx.x & 15, ty = threadIdx.x >> 4;
    char* tb = (char*)t;
#pragma unroll
    for (int i = 0; i < 4; i++) {
        int r = ty + i * 16;
        float4 v = *(const float4*)(s + (size_t)(r0 + r) * C + c0 + tx * 4);
        ushort4 o; o.x = f2bf(v.x); o.y = f2bf(v.y); o.z = f2bf(v.z); o.w = f2bf(v.w);
        *(ushort4*)(tb + swz(r, tx * 8)) = o;
    }
    __syncthreads();
    int cx = threadIdx.x & 7, cy = threadIdx.x >> 3;
#pragma unroll
    for (int i = 0; i < 2; i++) {
        int cc = cy + i * 32;
        u16x8_t o;
#pragma unroll
        for (int j = 0; j < 8; j++) {
            int rr = cx * 8 + j;
            o[j] = *(const ushort*)(tb + swz(rr, cc * 2));
        }
        *(u16x8_t*)(d + (size_t)(c0 + cc) * ldd + r0 + cx * 8) = o;
    }
}

// Router: f32 per-lane partials (32 terms/lane, abs err ~1e-7 << min top-2/3 logit gap
// ~3e-4 -> ranking identical to fp64), fp64 cross-lane combine/softmax/top-2.
// Also emits xb (bf16 of x) and per-block prob/logit partial sums (plain stores).
__device__ __forceinline__ void router_block(SMem& sm, int bid,
        const float* __restrict__ x, const float* __restrict__ gw, ushort* __restrict__ xbuf,
        int* __restrict__ topk_idx, float* __restrict__ topk_w,
        double* __restrict__ pparts, double* __restrict__ lparts) {
    const int wv = threadIdx.x >> 6, l = threadIdx.x & 63;
    const int tBase = bid * 8 + wv * 2;            // 4 waves x 2 tokens

    float acc0[NEXP], acc1[NEXP];
#pragma unroll
    for (int e = 0; e < NEXP; e++) { acc0[e] = 0.f; acc1[e] = 0.f; }

    const float* x0 = x + (size_t)tBase * DMODEL;
    const float* x1 = x0 + DMODEL;
    ushort* xo0 = xbuf + (size_t)tBase * DMODEL;
    ushort* xo1 = xo0 + DMODEL;

#pragma unroll
    for (int i = 0; i < 8; i++) {
        const int d0 = i * 256 + l * 4;
        float4 xa = *(const float4*)(x0 + d0);
        float4 xb4 = *(const float4*)(x1 + d0);
        ushort4 oa; oa.x = f2bf(xa.x); oa.y = f2bf(xa.y); oa.z = f2bf(xa.z); oa.w = f2bf(xa.w);
        ushort4 ob; ob.x = f2bf(xb4.x); ob.y = f2bf(xb4.y); ob.z = f2bf(xb4.z); ob.w = f2bf(xb4.w);
        *(ushort4*)(xo0 + d0) = oa;
        *(ushort4*)(xo1 + d0) = ob;
        const float xs0[4] = {xa.x, xa.y, xa.z, xa.w};
        const float xs1[4] = {xb4.x, xb4.y, xb4.z, xb4.w};
#pragma unroll
        for (int r = 0; r < 4; r++) {
            const float4* g = (const float4*)(gw + (size_t)(d0 + r) * NEXP);
            float4 q0 = g[0], q1 = g[1], q2 = g[2], q3 = g[3];
            const float gf[16] = {q0.x, q0.y, q0.z, q0.w, q1.x, q1.y, q1.z, q1.w,
                                  q2.x, q2.y, q2.z, q2.w, q3.x, q3.y, q3.z, q3.w};
#pragma unroll
            for (int e = 0; e < NEXP; e++) {
                acc0[e] += xs0[r] * gf[e];
                acc1[e] += xs1[r] * gf[e];
            }
        }
    }

#pragma unroll
    for (int e = 0; e < NEXP; e++) {
        acc0[e] += __shfl_xor(acc0[e], 32); acc0[e] += __shfl_xor(acc0[e], 16);
        acc1[e] += __shfl_xor(acc1[e], 32); acc1[e] += __shfl_xor(acc1[e], 16);
    }

    if (l < 16) {
#pragma unroll
        for (int e = 0; e < NEXP; e++) { sm.r.sred[wv][0][l][e] = acc0[e]; sm.r.sred[wv][1][l][e] = acc1[e]; }
    }
    __syncthreads();

    if (l < 32) {
        const int tok = l >> 4, e = l & 15;
        double lg = 0.0;
#pragma unroll
        for (int g = 0; g < 16; g++) lg += (double)sm.r.sred[wv][tok][g][e];

        double m = lg;
#pragma unroll
        for (int off = 8; off; off >>= 1) { double o = __shfl_xor(m, off); m = o > m ? o : m; }
        double pe = exp(lg - m);
        double ss = pe;
#pragma unroll
        for (int off = 8; off; off >>= 1) ss += __shfl_xor(ss, off);
        double p = pe / ss;

        double v = p; int ie = e;
#pragma unroll
        for (int off = 8; off; off >>= 1) {
            double ov = __shfl_xor(v, off); int oi = __shfl_xor(ie, off);
            if (ov > v || (ov == v && oi < ie)) { v = ov; ie = oi; }
        }
        double v2 = (e == ie) ? -1.0 : p; int ie2 = e;
#pragma unroll
        for (int off = 8; off; off >>= 1) {
            double ov = __shfl_xor(v2, off); int oi = __shfl_xor(ie2, off);
            if (ov > v2 || (ov == v2 && oi < ie2)) { v2 = ov; ie2 = oi; }
        }

        sm.r.sp[wv][tok][e] = p; sm.r.sl[wv][tok][e] = lg;

        if (e == 0) {
            int t = tBase + tok;
            double s2 = v + v2;
            topk_idx[t * 2] = ie;  topk_idx[t * 2 + 1] = ie2;
            topk_w[t * 2] = (float)(v / s2); topk_w[t * 2 + 1] = (float)(v2 / s2);
        }
    }
    __syncthreads();

    if (threadIdx.x < NEXP) {
        int e = threadIdx.x;
        double ps = 0.0, ls = 0.0;
#pragma unroll
        for (int w = 0; w < 4; w++) { ps += sm.r.sp[w][0][e] + sm.r.sp[w][1][e]; ls += sm.r.sl[w][0][e] + sm.r.sl[w][1][e]; }
        pparts[bid * NEXP + e] = ps;
        lparts[bid * NEXP + e] = ls;
    }
}

// segment boundaries
#define PB0 RBLK                 // 512   router
#define PB1 (PB0 + 1408)         // sw1: 22x32x2
#define PB2 (PB1 + 1408)         // sw2: 32x22x2
#define PB3 (PB2 + 11264)        // ew1: 22x32x16
#define PB4 (PB3 + 11264)        // ew2: 32x22x16  -> grid = 25856

__global__ __launch_bounds__(256) void prep_kernel(
        const float* __restrict__ x, const float* __restrict__ gw,
        const float* __restrict__ sw1, const float* __restrict__ sw2,
        const float* __restrict__ ew1, const float* __restrict__ ew2,
        ushort* __restrict__ xb, ushort* __restrict__ w1t, ushort* __restrict__ w2t,
        ushort* __restrict__ ew1t, ushort* __restrict__ ew2t,
        int* __restrict__ topk_idx, float* __restrict__ topk_w,
        double* __restrict__ pparts, double* __restrict__ lparts) {
    __shared__ SMem sm;
    int bid = blockIdx.x;
    if (bid < PB0) {
        router_block(sm, bid, x, gw, xb, topk_idx, topk_w, pparts, lparts);
    } else if (bid < PB1) {
        transpose_tile(sm.t, bid - PB0, sw1, w1t, HDIM, (long)DMODEL * HDIM, (long)HDIM * DMODEL,
                       DMODEL, HDIM / 64, DMODEL / 64);
    } else if (bid < PB2) {
        transpose_tile(sm.t, bid - PB1, sw2, w2t, DMODEL, (long)HDIM * DMODEL, (long)HDIM,
                       2 * HDIM, DMODEL / 64, HDIM / 64);
    } else if (bid < PB3) {
        transpose_tile(sm.t, bid - PB2, ew1, ew1t, HDIM, (long)DMODEL * HDIM, (long)HDIM * DMODEL,
                       DMODEL, HDIM / 64, DMODEL / 64);
    } else {
        transpose_tile(sm.t, bid - PB3, ew2, ew2t, DMODEL, (long)HDIM * DMODEL, (long)DMODEL * HDIM,
                       HDIM, DMODEL / 64, HDIM / 64);
    }
}

// ---------------- plan: histogram + tiles + aux + scatter (1 block) ----------------

__global__ __launch_bounds__(1024) void plan_kernel(
        const int* __restrict__ topk_idx, const float* __restrict__ topk_w,
        const double* __restrict__ pparts, const double* __restrict__ lparts,
        int* __restrict__ tile_expert, int* __restrict__ tile_row, int* __restrict__ meta,
        int* __restrict__ slot_token, float* __restrict__ slot_w, int* __restrict__ slot_of,
        float* __restrict__ out_aux) {
    __shared__ int hist[NEXP];
    __shared__ int curs[NEXP];
    __shared__ double pred[32][NEXP], lred[32][NEXP];
    __shared__ double paux[NEXP], laux[NEXP];
    const int tid = threadIdx.x;
    if (tid < NEXP) hist[tid] = 0;
    __syncthreads();
    for (int i = tid; i < T_TOT * 2; i += 1024) atomicAdd(&hist[topk_idx[i]], 1);
    for (int i = tid; i < MAXSLOT; i += 1024) { slot_token[i] = 0; slot_w[i] = 0.0f; }
    if (tid < 512) {
        int e = tid & 15, c = tid >> 4;     // 32 chunks of 16 blocks
        double ps = 0.0, ls = 0.0;
        for (int b = c * 16; b < c * 16 + 16; b++) { ps += pparts[b * NEXP + e]; ls += lparts[b * NEXP + e]; }
        pred[c][e] = ps; lred[c][e] = ls;
    }
    __syncthreads();
    if (tid < NEXP) {
        double ps = 0.0, ls = 0.0;
        for (int c = 0; c < 32; c++) { ps += pred[c][tid]; ls += lred[c][tid]; }
        paux[tid] = ps; laux[tid] = ls;
    }
    __syncthreads();
    if (tid == 0) {
        int off = 0, nt = 0;
        for (int e = 0; e < NEXP; e++) {
            curs[e] = off;
            int tiles = (hist[e] + 127) >> 7;
            for (int j = 0; j < tiles; j++) { tile_expert[nt] = e; tile_row[nt] = off + j * 128; nt++; }
            off += tiles * 128;
        }
        meta[0] = nt; meta[1] = off;
        double aux = 0.0;
        for (int e = 0; e < NEXP; e++)
            aux += (paux[e] / (double)T_TOT) * (laux[e] / (double)T_TOT);
        out_aux[0] = (float)(aux * (double)NEXP);
    }
    __syncthreads();
    for (int i = tid; i < T_TOT * 2; i += 1024) {
        int e = topk_idx[i];
        int pos = atomicAdd(&curs[e], 1);
        slot_token[pos] = i >> 1;
        slot_w[pos] = topk_w[i];
        slot_of[i] = pos;
    }
}

// ---------------- GEMM core: 128x128 tile, BK=32, 4 waves, mfma 16x16x32 bf16 ----------------
// Double-buffered LDS (2 x 16KB halves), ONE barrier per K-iter.

template<bool INDIRECT_A>
__device__ __forceinline__ void gemm_tile_core(const ushort* __restrict__ A, const ushort* __restrict__ B,
                                               int lda, int ldb, int K, int m0, int n0,
                                               const int* __restrict__ rowmap,
                                               f32x4_t acc[4][4], ushort* lds) {
    const int tid = threadIdx.x;
    const int w = tid >> 6, l = tid & 63;
    const int c0 = w * 2, c1 = c0 + 1;       // each wave stages 2 of 8 1KB chunks of A and of B
    const int subrow = l >> 2;
    const int kc = (l & 3) * 8;
    int ar0 = c0 * 16 + subrow, ar1 = c1 * 16 + subrow;
    long ga0, ga1;
    if (INDIRECT_A) { ga0 = (long)rowmap[m0 + ar0]; ga1 = (long)rowmap[m0 + ar1]; }
    else            { ga0 = (long)(m0 + ar0);       ga1 = (long)(m0 + ar1); }
    const ushort* pa0 = A + ga0 * lda + kc;
    const ushort* pa1 = A + ga1 * lda + kc;
    const ushort* pb0 = B + (long)(n0 + ar0) * ldb + kc;
    const ushort* pb1 = B + (long)(n0 + ar1) * ldb + kc;
    const int wm = w & 1, wn = w >> 1;
    const int lrow = l & 15, quad = l >> 4;

    {   // prologue: stage k=0 into half 0
        ushort* d0 = lds + c0 * 512;
        ushort* d1 = lds + c1 * 512;
        async16(pa0, d0); async16(pa1, d1);
        async16(pb0, d0 + 4096); async16(pb1, d1 + 4096);
    }
    int cur = 0;
    for (int kt = 0; kt < K; kt += 32) {
        __syncthreads();                     // half `cur` staged (vmcnt drained here)
        if (kt + 32 < K) {                   // prefetch next tile into other half
            pa0 += 32; pa1 += 32; pb0 += 32; pb1 += 32;
            ushort* e0 = lds + (cur ^ 1) * 8192 + c0 * 512;
            ushort* e1 = lds + (cur ^ 1) * 8192 + c1 * 512;
            async16(pa0, e0); async16(pa1, e1);
            async16(pb0, e0 + 4096); async16(pb1, e1 + 4096);
        }
        const ushort* As = lds + cur * 8192;
        const ushort* Bs = As + 4096;
        bf16x8_t a[4], b[4];
#pragma unroll
        for (int mi = 0; mi < 4; mi++)
            a[mi] = *(const bf16x8_t*)(As + (wm * 64 + mi * 16 + lrow) * 32 + quad * 8);
#pragma unroll
        for (int ni = 0; ni < 4; ni++)
            b[ni] = *(const bf16x8_t*)(Bs + (wn * 64 + ni * 16 + lrow) * 32 + quad * 8);
#pragma unroll
        for (int mi = 0; mi < 4; mi++)
#pragma unroll
            for (int ni = 0; ni < 4; ni++)
                acc[mi][ni] = __builtin_amdgcn_mfma_f32_16x16x32_bf16(a[mi], b[ni], acc[mi][ni], 0, 0, 0);
        cur ^= 1;
    }
}

// P1: [0,704) shared GEMM1 (z over 2 experts) ++ [704, 704+880) routed GEMM1.
__global__ __launch_bounds__(256, 3) void gemm_p1(const ushort* __restrict__ xb,
        const ushort* __restrict__ w1t, const ushort* __restrict__ ew1t,
        ushort* __restrict__ h, ushort* __restrict__ hg,
        const int* __restrict__ tile_expert, const int* __restrict__ tile_row,
        const int* __restrict__ meta, const int* __restrict__ slot_token) {
    __shared__ ushort lds[16384];
    f32x4_t acc[4][4];
#pragma unroll
    for (int mi = 0; mi < 4; mi++)
#pragma unroll
        for (int ni = 0; ni < 4; ni++) acc[mi][ni] = (f32x4_t){0.f, 0.f, 0.f, 0.f};

    const int bid = blockIdx.x;
    ushort* C; int ldc, m0, n0, colBase;
    if (bid < 704) {
        int z = bid / 352, rem = bid % 352;
        m0 = (rem % 32) * 128; n0 = (rem / 32) * 128;
        gemm_tile_core<false>(xb, w1t + (long)z * HDIM * DMODEL, DMODEL, DMODEL, DMODEL,
                              m0, n0, nullptr, acc, lds);
        C = h; ldc = 2 * HDIM; colBase = z * HDIM + n0;
    } else {
        int r = bid - 704;
        int tile = r % MAXTILE; n0 = (r / MAXTILE) * 128;
        if (tile >= meta[0]) return;
        int e = tile_expert[tile]; m0 = tile_row[tile];
        gemm_tile_core<true>(xb, ew1t + (long)e * HDIM * DMODEL, DMODEL, DMODEL, DMODEL,
                             m0, n0, slot_token, acc, lds);
        C = hg; ldc = HDIM; colBase = n0;
    }

    const int w = threadIdx.x >> 6, l = threadIdx.x & 63;
    const int wm = w & 1, wn = w >> 1, quad = l >> 4, lcol = l & 15;
#pragma unroll
    for (int mi = 0; mi < 4; mi++) {
        int rowb = m0 + wm * 64 + mi * 16 + quad * 4;
#pragma unroll
        for (int ni = 0; ni < 4; ni++) {
            int col = colBase + wn * 64 + ni * 16 + lcol;
#pragma unroll
            for (int r = 0; r < 4; r++)
                C[(long)(rowb + r) * ldc + col] = f2bf(silu(acc[mi][ni][r]));
        }
    }
}

// P2: [0,512) shared GEMM2 (f32 -> out) ++ [512, 512+1280) routed GEMM2 (w*acc bf16 -> ro).
__global__ __launch_bounds__(256, 3) void gemm_p2(const ushort* __restrict__ h,
        const ushort* __restrict__ w2t, const ushort* __restrict__ hg, const ushort* __restrict__ ew2t,
        float* __restrict__ out, ushort* __restrict__ ro,
        const int* __restrict__ tile_expert, const int* __restrict__ tile_row,
        const int* __restrict__ meta, const float* __restrict__ slot_w) {
    __shared__ ushort lds[16384];
    f32x4_t acc[4][4];
#pragma unroll
    for (int mi = 0; mi < 4; mi++)
#pragma unroll
        for (int ni = 0; ni < 4; ni++) acc[mi][ni] = (f32x4_t){0.f, 0.f, 0.f, 0.f};

    const int bid = blockIdx.x;
    const int w = threadIdx.x >> 6, l = threadIdx.x & 63;
    const int wm = w & 1, wn = w >> 1, quad = l >> 4, lcol = l & 15;

    if (bid < 512) {
        int m0 = (bid % 32) * 128, n0 = (bid / 32) * 128;
        gemm_tile_core<false>(h, w2t, 2 * HDIM, 2 * HDIM, 2 * HDIM, m0, n0, nullptr, acc, lds);
#pragma unroll
        for (int mi = 0; mi < 4; mi++) {
            int rowb = m0 + wm * 64 + mi * 16 + quad * 4;
#pragma unroll
            for (int ni = 0; ni < 4; ni++) {
                int col = n0 + wn * 64 + ni * 16 + lcol;
#pragma unroll
                for (int r = 0; r < 4; r++)
                    out[(long)(rowb + r) * DMODEL + col] = acc[mi][ni][r];
            }
        }
    } else {
        int r0 = bid - 512;
        int tile = r0 % MAXTILE; int n0 = (r0 / MAXTILE) * 128;
        if (tile >= meta[0]) return;
        int e = tile_expert[tile]; int m0 = tile_row[tile];
        gemm_tile_core<false>(hg, ew2t + (long)e * DMODEL * HDIM, HDIM, HDIM, HDIM,
                              m0, n0, nullptr, acc, lds);
#pragma unroll
        for (int mi = 0; mi < 4; mi++) {
            int rowb = m0 + wm * 64 + mi * 16 + quad * 4;
#pragma unroll
            for (int ni = 0; ni < 4; ni++) {
                int col = n0 + wn * 64 + ni * 16 + lcol;
#pragma unroll
                for (int r = 0; r < 4; r++) {
                    int row = rowb + r;
                    ro[(long)row * DMODEL + col] = f2bf(acc[mi][ni][r] * slot_w[row]);
                }
            }
        }
    }
}

// out[t,:] += ro[slot1(t),:] + ro[slot2(t),:]   (weights already folded into ro)
__global__ __launch_bounds__(256) void combine_kernel(float* __restrict__ out, const ushort* __restrict__ ro,
                                                      const int* __restrict__ slot_of) {
    int t = blockIdx.x;
    int s1 = slot_of[t * 2], s2 = slot_of[t * 2 + 1];
    const u16x8_t* r1 = (const u16x8_t*)(ro + (size_t)s1 * DMODEL);
    const u16x8_t* r2 = (const u16x8_t*)(ro + (size_t)s2 * DMODEL);
    int i = threadIdx.x;                      // DMODEL/8 = 256 exactly
    u16x8_t a = r1[i], b = r2[i];
    float4* o = (float4*)(out + (size_t)t * DMODEL) + i * 2;
    float4 o0 = o[0], o1 = o[1];
    o0.x += bf2f(a[0]) + bf2f(b[0]); o0.y += bf2f(a[1]) + bf2f(b[1]);
    o0.z += bf2f(a[2]) + bf2f(b[2]); o0.w += bf2f(a[3]) + bf2f(b[3]);
    o1.x += bf2f(a[4]) + bf2f(b[4]); o1.y += bf2f(a[5]) + bf2f(b[5]);
    o1.z += bf2f(a[6]) + bf2f(b[6]); o1.w += bf2f(a[7]) + bf2f(b[7]);
    o[0] = o0; o[1] = o1;
}

// ---------------- launch ----------------

extern "C" void kernel_launch(void* const* d_in, const int* in_sizes, int n_in,
                              void* d_out, int out_size, void* d_ws, size_t ws_size,
                              hipStream_t stream) {
    const float* x   = (const float*)d_in[0];
    const float* gw  = (const float*)d_in[1];
    const float* sw1 = (const float*)d_in[2];
    const float* sw2 = (const float*)d_in[3];
    const float* ew1 = (const float*)d_in[4];
    const float* ew2 = (const float*)d_in[5];
    float* out = (float*)d_out;

    char* p = (char*)d_ws;
    auto alloc = [&](size_t bytes) { char* r = p; p += (bytes + 511) & ~(size_t)511; return r; };
    ushort* xb    = (ushort*)alloc((size_t)T_TOT * DMODEL * 2);
    ushort* w1t   = (ushort*)alloc((size_t)2 * HDIM * DMODEL * 2);
    ushort* w2t   = (ushort*)alloc((size_t)DMODEL * 2 * HDIM * 2);
    ushort* ew1t  = (ushort*)alloc((size_t)NEXP * HDIM * DMODEL * 2);
    ushort* ew2t  = (ushort*)alloc((size_t)NEXP * DMODEL * HDIM * 2);
    ushort* h     = (ushort*)alloc((size_t)T_TOT * 2 * HDIM * 2);
    ushort* hg    = (ushort*)alloc((size_t)MAXSLOT * HDIM * 2);
    ushort* ro    = (ushort*)alloc((size_t)MAXSLOT * DMODEL * 2);   // routed weighted rows, bf16
    int*    slot_token = (int*)alloc(MAXSLOT * 4);
    float*  slot_w     = (float*)alloc(MAXSLOT * 4);
    int*    slot_of    = (int*)alloc(T_TOT * 2 * 4);
    int*    topk_idx   = (int*)alloc(T_TOT * 2 * 4);
    float*  topk_w     = (float*)alloc(T_TOT * 2 * 4);
    int*    tile_expert= (int*)alloc(512);
    int*    tile_row   = (int*)alloc(512);
    int*    meta       = (int*)alloc(64);
    double* pparts     = (double*)alloc((size_t)RBLK * NEXP * 8);
    double* lparts     = (double*)alloc((size_t)RBLK * NEXP * 8);

    // 1) transposes + router (+ xb emission, per-block aux partials)
    prep_kernel<<<PB4, 256, 0, stream>>>(x, gw, sw1, sw2, ew1, ew2,
                                         xb, w1t, w2t, ew1t, ew2t,
                                         topk_idx, topk_w, pparts, lparts);
    // 2) histogram + tiles + aux + scatter
    plan_kernel<<<1, 1024, 0, stream>>>(topk_idx, topk_w, pparts, lparts,
                                        tile_expert, tile_row, meta,
                                        slot_token, slot_w, slot_of, out + (size_t)T_TOT * DMODEL);
    // 3) shared GEMM1 + routed GEMM1
    gemm_p1<<<704 + MAXTILE * (HDIM / 128), 256, 0, stream>>>(
        xb, w1t, ew1t, h, hg, tile_expert, tile_row, meta, slot_token);
    // 4) shared GEMM2 + routed GEMM2
    gemm_p2<<<512 + MAXTILE * (DMODEL / 128), 256, 0, stream>>>(
        h, w2t, hg, ew2t, out, ro, tile_expert, tile_row, meta, slot_w);
    // 5) combine: out[t] += ro[slot1(t)] + ro[slot2(t)]
    combine_kernel<<<T_TOT, 256, 0, stream>>>(out, ro, slot_of);
}